// Round 1
// baseline (84.814 us; speedup 1.0000x reference)
//
#include <hip/hip_runtime.h>

namespace {
constexpr int BATCH = 8;
constexpr int NPTS  = 16384;
constexpr int CH    = 64;
constexpr int KNN   = 16;
constexpr int ROWS  = BATCH * NPTS;
constexpr float EPS = 1e-5f;
constexpr int CHUNKS = 128;           // blocks per batch
constexpr int RPB   = NPTS / CHUNKS;  // rows per block = 128
}

// K1: gather -> max(seeded 0 == relu) -> y = agg @ W ; partial BN stats.
// grid = 8*CHUNKS blocks of 256 (4 waves). batch = blockIdx%8 aligns with XCD
// round-robin so each batch's 4.19MB x-slab stays in one XCD's L2.
__global__ __launch_bounds__(256)
void k_fused(const float* __restrict__ x, const int* __restrict__ idx,
             const float* __restrict__ W, float* __restrict__ y,
             float* __restrict__ stats)
{
    const int lane  = threadIdx.x & 63;
    const int wave  = threadIdx.x >> 6;
    const int batch = blockIdx.x & 7;
    const int chunk = blockIdx.x >> 3;

    const float* __restrict__ xb = x   + (size_t)batch * NPTS * CH;
    const int*   __restrict__ ib = idx + (size_t)batch * NPTS * KNN;
    float*       __restrict__ yb = y   + (size_t)batch * NPTS * CH;

    // W column for this lane (o = lane): Wc[c] = W[c][lane]. 64 VGPRs, loaded
    // once per block with coalesced 256B wave reads.
    float Wc[CH];
#pragma unroll
    for (int c = 0; c < CH; ++c) Wc[c] = W[c * CH + lane];

    float s1 = 0.f, s2 = 0.f;
    const int row0 = chunk * RPB;

    for (int r = wave; r < RPB; r += 4) {
        const int row = row0 + r;
        const int4* ip = (const int4*)(ib + (size_t)row * KNN);
        int4 q0 = ip[0];
        int4 q1 = ip[1];
        int4 q2 = ip[2];
        int4 q3 = ip[3];

        float acc = 0.f;  // relu(max_k) == max(0, max_k): seed with 0
#define G(v) acc = fmaxf(acc, xb[(size_t)(unsigned)(v) * CH + lane]);
        G(q0.x) G(q0.y) G(q0.z) G(q0.w)
        G(q1.x) G(q1.y) G(q1.z) G(q1.w)
        G(q2.x) G(q2.y) G(q2.z) G(q2.w)
        G(q3.x) G(q3.y) G(q3.z) G(q3.w)
#undef G

        // y[row][lane] = sum_c agg[c] * W[c][lane]  via SGPR broadcast
        const int ab = (int)__float_as_uint(acc);
        float yv = 0.f;
#pragma unroll
        for (int c = 0; c < CH; ++c) {
            float a = __uint_as_float((unsigned)__builtin_amdgcn_readlane(ab, c));
            yv = fmaf(a, Wc[c], yv);
        }
        yb[(size_t)row * CH + lane] = yv;
        s1 += yv;
        s2 = fmaf(yv, yv, s2);
    }

    // block-level reduction of per-lane (column = lane) partial sums
    __shared__ float red[8][64];
    red[wave][lane]     = s1;
    red[4 + wave][lane] = s2;
    __syncthreads();
    if (wave == 0) {
        float t1 = red[0][lane] + red[1][lane] + red[2][lane] + red[3][lane];
        float t2 = red[4][lane] + red[5][lane] + red[6][lane] + red[7][lane];
        atomicAdd(&stats[lane],      t1);
        atomicAdd(&stats[64 + lane], t2);
    }
}

// K2: finalize BN scale/bias (64 columns)
__global__ void k_finalize(const float* __restrict__ stats,
                           const float* __restrict__ gamma,
                           const float* __restrict__ beta,
                           float* __restrict__ sb)
{
    const int l = threadIdx.x;
    if (l >= CH) return;
    const float inv_n = 1.0f / (float)ROWS;
    float mean = stats[l] * inv_n;
    float ex2  = stats[64 + l] * inv_n;
    float var  = ex2 - mean * mean;
    float scale = gamma[l] * rsqrtf(var + EPS);
    sb[l]      = scale;
    sb[64 + l] = beta[l] - mean * scale;
}

// K3: in-place normalize y (float4, grid-stride)
__global__ __launch_bounds__(256)
void k_norm(float* __restrict__ y, const float* __restrict__ sb)
{
    __shared__ float s[CH], b[CH];
    if (threadIdx.x < CH) {
        s[threadIdx.x] = sb[threadIdx.x];
        b[threadIdx.x] = sb[64 + threadIdx.x];
    }
    __syncthreads();

    float4* p = (float4*)y;
    const size_t ntot = (size_t)ROWS * CH / 4;   // 2M float4
    size_t i = (size_t)blockIdx.x * blockDim.x + threadIdx.x;
    const size_t stride = (size_t)gridDim.x * blockDim.x;
    for (; i < ntot; i += stride) {
        float4 v = p[i];
        const int c0 = ((int)i & 15) * 4;        // 16 float4 per 64ch row
        v.x = fmaf(v.x, s[c0],     b[c0]);
        v.y = fmaf(v.y, s[c0 + 1], b[c0 + 1]);
        v.z = fmaf(v.z, s[c0 + 2], b[c0 + 2]);
        v.w = fmaf(v.w, s[c0 + 3], b[c0 + 3]);
        p[i] = v;
    }
}

extern "C" void kernel_launch(void* const* d_in, const int* in_sizes, int n_in,
                              void* d_out, int out_size, void* d_ws, size_t ws_size,
                              hipStream_t stream)
{
    const float* x     = (const float*)d_in[0];
    const int*   idx   = (const int*)d_in[1];
    const float* W     = (const float*)d_in[2];
    const float* gamma = (const float*)d_in[3];
    const float* beta  = (const float*)d_in[4];

    float* y     = (float*)d_out;          // y lives in d_out; normalized in place
    float* stats = (float*)d_ws;           // [0..64) sum, [64..128) sumsq
    float* sb    = stats + 128;            // [0..64) scale, [64..128) bias

    hipMemsetAsync(stats, 0, 128 * sizeof(float), stream);

    k_fused<<<dim3(8 * CHUNKS), dim3(256), 0, stream>>>(x, idx, W, y, stats);
    k_finalize<<<dim3(1), dim3(64), 0, stream>>>(stats, gamma, beta, sb);
    k_norm<<<dim3(2048), dim3(256), 0, stream>>>(y, sb);
}